// Round 6
// baseline (124.760 us; speedup 1.0000x reference)
//
#include <hip/hip_runtime.h>
#include <math.h>

#define N_IN 256
#define BATCH 4096
#define GRID 2048
#define BLOCK 256
#define NROWS (BATCH * N_IN * 4)          // 4,194,304 float4 rows
#define ITERS (NROWS / (GRID * BLOCK))    // = 8, compile-time

// ---------------------------------------------------------------------------
// Kernel 1: build the 256 4x4 world matrices into workspace (f64 for fidelity).
// One block, 256 threads, once per launch — ~2 µs, off the hot path.
// ---------------------------------------------------------------------------
__global__ void build_wm_kernel(const float* __restrict__ aW,
                                const float* __restrict__ uW,
                                const float* __restrict__ tW,
                                float* __restrict__ WM) {
    int n = threadIdx.x;
    if (n >= N_IN) return;

    double a = (double)aW[n];
    double u0 = 1.0 / (1.0 + exp(-(double)uW[n * 3 + 0]));
    double u1 = 1.0 / (1.0 + exp(-(double)uW[n * 3 + 1]));
    double u2 = 1.0 / (1.0 + exp(-(double)uW[n * 3 + 2]));
    double inv_norm = 1.0 / sqrt(u0 * u0 + u1 * u1 + u2 * u2);
    double ux = u0 * inv_norm, uy = u1 * inv_norm, uz = u2 * inv_norm;

    double sa = sin(a), ca = cos(a);

    double R00 = (1.0 - ux * ux) * ca + ux * ux;
    double R01 = -uz * sa - ux * uy * ca + ux * uy;
    double R02 =  uy * sa - ux * uz * ca + ux * uz;
    double R10 =  uz * sa - uy * ux * ca + uy * ux;
    double R11 = (1.0 - uy * uy) * ca + uy * uy;
    double R12 = -ux * sa - uy * uz * ca + uy * uz;
    double R20 = -uy * sa - uz * ux * ca + uz * ux;
    double R21 =  ux * sa - uz * uy * ca + uz * uy;
    double R22 = (1.0 - uz * uz) * ca + uz * uz;

    float* w = WM + n * 16;
    w[0]  = (float)R00; w[1]  = (float)R01; w[2]  = (float)R02; w[3]  = tW[n * 3 + 0];
    w[4]  = (float)R10; w[5]  = (float)R11; w[6]  = (float)R12; w[7]  = tW[n * 3 + 1];
    w[8]  = (float)R20; w[9]  = (float)R21; w[10] = (float)R22; w[11] = tW[n * 3 + 2];
    w[12] = 0.0f;       w[13] = 0.0f;       w[14] = 0.0f;       w[15] = 1.0f;
}

// ---------------------------------------------------------------------------
// Kernel 2: out_row = I_row (1x4) @ WM[n] (4x4), one float4 row per thread.
// Grid-stride = GRID*BLOCK rows = 131072 matrices == 0 (mod 256), so each
// thread's matrix index n is LOOP-INVARIANT: load WM[n] into 16 VGPRs once.
// Hot loop = 1 global_load_dwordx4 + 16 v_fma_f32 + 1 global_store_dwordx4
// per 32 B HBM — identical VMEM profile to a pure copy kernel (~6.4 TB/s).
// Compile-time trip count (8) -> full unroll, 8 loads in flight per thread.
// ---------------------------------------------------------------------------
__global__ __launch_bounds__(BLOCK) void apply_wm_kernel(
        const float4* __restrict__ I,
        const float4* __restrict__ WMg,   // 256 matrices, 4 float4 rows each
        float4* __restrict__ O) {
    int idx0 = blockIdx.x * BLOCK + threadIdx.x;
    int n = (idx0 >> 2) & (N_IN - 1);     // loop-invariant matrix id
    const float4* w = WMg + n * 4;
    float4 w0 = w[0], w1 = w[1], w2 = w[2], w3 = w[3];  // L1/L2 hits, once

    #pragma unroll
    for (int it = 0; it < ITERS; ++it) {
        int idx = idx0 + it * (GRID * BLOCK);
        float4 r = I[idx];
        float4 o;
        o.x = r.x * w0.x + r.y * w1.x + r.z * w2.x + r.w * w3.x;
        o.y = r.x * w0.y + r.y * w1.y + r.z * w2.y + r.w * w3.y;
        o.z = r.x * w0.z + r.y * w1.z + r.z * w2.z + r.w * w3.z;
        o.w = r.x * w0.w + r.y * w1.w + r.z * w2.w + r.w * w3.w;
        O[idx] = o;
    }
}

extern "C" void kernel_launch(void* const* d_in, const int* in_sizes, int n_in,
                              void* d_out, int out_size, void* d_ws, size_t ws_size,
                              hipStream_t stream) {
    const float* I  = (const float*)d_in[0];   // (4096, 256, 4, 4)
    const float* aW = (const float*)d_in[1];   // (256, 1, 1)
    const float* uW = (const float*)d_in[2];   // (256, 1, 3)
    const float* tW = (const float*)d_in[3];   // (256, 1, 3)
    float* out = (float*)d_out;
    float* WM = (float*)d_ws;                  // 256 * 16 floats = 16 KB

    build_wm_kernel<<<1, N_IN, 0, stream>>>(aW, uW, tW, WM);

    apply_wm_kernel<<<GRID, BLOCK, 0, stream>>>(
        (const float4*)I, (const float4*)WM, (float4*)out);
}

// Round 7
// 119.376 us; speedup vs baseline: 1.0451x; 1.0451x over previous
//
#include <hip/hip_runtime.h>
#include <math.h>

#define N_IN 256
#define BATCH 4096
#define GRID 2048
#define BLOCK 256
#define NROWS (BATCH * N_IN * 4)          // 4,194,304 float4 rows
#define STRIDE (GRID * BLOCK)
#define ITERS (NROWS / STRIDE)            // = 8, compile-time

// ---------------------------------------------------------------------------
// Single fused kernel. One float4 row per thread per iteration.
// Grid-stride = 524288 rows = 131072 matrices == 0 (mod 256), so each
// thread's matrix index n = (idx0>>2)&255 is LOOP-INVARIANT. Each thread
// builds WM[n] once in registers (f64 Rodrigues, same math as the previous
// passing build kernel; 4 threads/matrix redundant — ~200 f64 ops, hidden
// under the HBM stream since the I loads don't depend on it).
// Hot loop: 1 global_load_dwordx4 + 16 v_fma_f32 + 1 global_store_dwordx4
// per 32 B HBM — copy-equivalent VMEM profile. No LDS, no barrier, and no
// second dispatch (saves the build kernel launch + graph-node gap).
// ---------------------------------------------------------------------------
__global__ __launch_bounds__(BLOCK) void fused_wm_apply_kernel(
        const float4* __restrict__ I,
        const float*  __restrict__ aW,
        const float*  __restrict__ uW,
        const float*  __restrict__ tW,
        float4* __restrict__ O) {
    int idx0 = blockIdx.x * BLOCK + threadIdx.x;
    int n = (idx0 >> 2) & (N_IN - 1);     // loop-invariant matrix id

    // --- build WM[n] in registers (identical f64 math to prior rounds) ---
    double a = (double)aW[n];
    double u0 = 1.0 / (1.0 + exp(-(double)uW[n * 3 + 0]));
    double u1 = 1.0 / (1.0 + exp(-(double)uW[n * 3 + 1]));
    double u2 = 1.0 / (1.0 + exp(-(double)uW[n * 3 + 2]));
    double inv_norm = 1.0 / sqrt(u0 * u0 + u1 * u1 + u2 * u2);
    double ux = u0 * inv_norm, uy = u1 * inv_norm, uz = u2 * inv_norm;
    double sa = sin(a), ca = cos(a);

    float4 w0, w1, w2, w3;
    w0.x = (float)((1.0 - ux * ux) * ca + ux * ux);
    w0.y = (float)(-uz * sa - ux * uy * ca + ux * uy);
    w0.z = (float)( uy * sa - ux * uz * ca + ux * uz);
    w0.w = tW[n * 3 + 0];
    w1.x = (float)( uz * sa - uy * ux * ca + uy * ux);
    w1.y = (float)((1.0 - uy * uy) * ca + uy * uy);
    w1.z = (float)(-ux * sa - uy * uz * ca + uy * uz);
    w1.w = tW[n * 3 + 1];
    w2.x = (float)(-uy * sa - uz * ux * ca + uz * ux);
    w2.y = (float)( ux * sa - uz * uy * ca + uz * uy);
    w2.z = (float)((1.0 - uz * uz) * ca + uz * uz);
    w2.w = tW[n * 3 + 2];
    w3.x = 0.0f; w3.y = 0.0f; w3.z = 0.0f; w3.w = 1.0f;

    // --- streaming apply: out_row = I_row (1x4) @ WM (4x4) ---
    #pragma unroll
    for (int it = 0; it < ITERS; ++it) {
        int idx = idx0 + it * STRIDE;
        float4 r = I[idx];
        float4 o;
        o.x = r.x * w0.x + r.y * w1.x + r.z * w2.x;           // w3.x == 0
        o.y = r.x * w0.y + r.y * w1.y + r.z * w2.y;           // w3.y == 0
        o.z = r.x * w0.z + r.y * w1.z + r.z * w2.z;           // w3.z == 0
        o.w = r.x * w0.w + r.y * w1.w + r.z * w2.w + r.w;     // w3.w == 1
        O[idx] = o;
    }
}

extern "C" void kernel_launch(void* const* d_in, const int* in_sizes, int n_in,
                              void* d_out, int out_size, void* d_ws, size_t ws_size,
                              hipStream_t stream) {
    const float* I  = (const float*)d_in[0];   // (4096, 256, 4, 4)
    const float* aW = (const float*)d_in[1];   // (256, 1, 1)
    const float* uW = (const float*)d_in[2];   // (256, 1, 3)
    const float* tW = (const float*)d_in[3];   // (256, 1, 3)
    float* out = (float*)d_out;

    fused_wm_apply_kernel<<<GRID, BLOCK, 0, stream>>>(
        (const float4*)I, aW, uW, tW, (float4*)out);
}

// Round 9
// 117.436 us; speedup vs baseline: 1.0624x; 1.0165x over previous
//
#include <hip/hip_runtime.h>
#include <math.h>

#define N_IN 256
#define BATCH 4096
#define GRID 512
#define BLOCK 256
#define NROWS (BATCH * N_IN * 4)          // 4,194,304 float4 rows
#define STRIDE (GRID * BLOCK)             // 131072 rows = 32768 matrices ≡ 0 mod 256
#define ITERS (NROWS / STRIDE)            // = 32, compile-time

// ---------------------------------------------------------------------------
// Single fused kernel. One float4 row per thread per iteration.
// Grid-stride keeps each thread's matrix index n = (idx0>>2)&255 LOOP-
// INVARIANT, so WM[n] is built once per thread in registers (f64 Rodrigues,
// formula identical to all prior passing rounds).
// GRID=512 (was 2048): 4x fewer threads -> 4x smaller chip-wide f64-trig
// burst (~1.3 us), while 2 blocks/CU x 8 waves x 8 outstanding dwordx4
// loads (~48 KB/CU in flight) still covers the ~9.4 KB needed to sustain
// HBM rate. Hot loop: 1 global_load_dwordx4 + ~12 v_fma_f32 +
// 1 global_store_dwordx4 per 32 B HBM — copy-equivalent VMEM profile.
// ---------------------------------------------------------------------------
__global__ __launch_bounds__(BLOCK) void fused_wm_apply_kernel(
        const float4* __restrict__ I,
        const float*  __restrict__ aW,
        const float*  __restrict__ uW,
        const float*  __restrict__ tW,
        float4* __restrict__ O) {
    int idx0 = blockIdx.x * BLOCK + threadIdx.x;
    int n = (idx0 >> 2) & (N_IN - 1);     // loop-invariant matrix id

    // --- build WM[n] in registers (identical f64 math to prior rounds) ---
    double a = (double)aW[n];
    double u0 = 1.0 / (1.0 + exp(-(double)uW[n * 3 + 0]));
    double u1 = 1.0 / (1.0 + exp(-(double)uW[n * 3 + 1]));
    double u2 = 1.0 / (1.0 + exp(-(double)uW[n * 3 + 2]));
    double inv_norm = 1.0 / sqrt(u0 * u0 + u1 * u1 + u2 * u2);
    double ux = u0 * inv_norm, uy = u1 * inv_norm, uz = u2 * inv_norm;
    double sa = sin(a), ca = cos(a);

    float4 w0, w1, w2;
    w0.x = (float)((1.0 - ux * ux) * ca + ux * ux);
    w0.y = (float)(-uz * sa - ux * uy * ca + ux * uy);
    w0.z = (float)( uy * sa - ux * uz * ca + ux * uz);
    w0.w = tW[n * 3 + 0];
    w1.x = (float)( uz * sa - uy * ux * ca + uy * ux);
    w1.y = (float)((1.0 - uy * uy) * ca + uy * uy);
    w1.z = (float)(-ux * sa - uy * uz * ca + uy * uz);
    w1.w = tW[n * 3 + 1];
    w2.x = (float)(-uy * sa - uz * ux * ca + uz * ux);
    w2.y = (float)( ux * sa - uz * uy * ca + uz * uy);
    w2.z = (float)((1.0 - uz * uz) * ca + uz * uz);
    w2.w = tW[n * 3 + 2];
    // row 3 of WM is [0,0,0,1] — folded into the FMAs below.

    // --- streaming apply: out_row = I_row (1x4) @ WM (4x4) ---
    #pragma unroll 8
    for (int it = 0; it < ITERS; ++it) {
        int idx = idx0 + it * STRIDE;
        float4 r = I[idx];
        float4 o;
        o.x = r.x * w0.x + r.y * w1.x + r.z * w2.x;           // + r.w * 0
        o.y = r.x * w0.y + r.y * w1.y + r.z * w2.y;           // + r.w * 0
        o.z = r.x * w0.z + r.y * w1.z + r.z * w2.z;           // + r.w * 0
        o.w = r.x * w0.w + r.y * w1.w + r.z * w2.w + r.w;     // + r.w * 1
        O[idx] = o;
    }
}

extern "C" void kernel_launch(void* const* d_in, const int* in_sizes, int n_in,
                              void* d_out, int out_size, void* d_ws, size_t ws_size,
                              hipStream_t stream) {
    const float* I  = (const float*)d_in[0];   // (4096, 256, 4, 4)
    const float* aW = (const float*)d_in[1];   // (256, 1, 1)
    const float* uW = (const float*)d_in[2];   // (256, 1, 3)
    const float* tW = (const float*)d_in[3];   // (256, 1, 3)
    float* out = (float*)d_out;

    fused_wm_apply_kernel<<<GRID, BLOCK, 0, stream>>>(
        (const float4*)I, aW, uW, tW, (float4*)out);
}